// Round 7
// baseline (559.795 us; speedup 1.0000x reference)
//
#include <hip/hip_runtime.h>
#include <hip/hip_bf16.h>
#include <cstdint>

typedef __bf16 bf16_t;
typedef __attribute__((ext_vector_type(8))) __bf16 bf16x8;
typedef __attribute__((ext_vector_type(4))) __bf16 bf16x4;
typedef __attribute__((ext_vector_type(4))) float f32x4;

#define NEXP 8
#define DK   2048
#define DN   2816
#define DN2  5632
#define NP   8192
#define PPE  1024

// ---------- gather x rows by sorted_token_ids, convert to bf16 ----------
__global__ void k_gather(const float* __restrict__ x, const int* __restrict__ ids,
                         bf16_t* __restrict__ xg) {
    int i = blockIdx.x * blockDim.x + threadIdx.x;
    if (i >= NP * (DK / 4)) return;
    int p  = i >> 9;
    int c4 = i & 511;
    int tok = ids[p];
    float4 v = reinterpret_cast<const float4*>(x + (size_t)tok * DK)[c4];
    bf16x4 o = { (bf16_t)v.x, (bf16_t)v.y, (bf16_t)v.z, (bf16_t)v.w };
    *reinterpret_cast<bf16x4*>(xg + (size_t)p * DK + c4 * 4) = o;
}

// ---------- async global->LDS, 16B per lane (wave-uniform LDS base) ----------
__device__ __forceinline__ void gl2lds16(const bf16_t* g, bf16_t* l) {
    __builtin_amdgcn_global_load_lds(
        (__attribute__((address_space(1))) void*)(const_cast<bf16_t*>(g)),
        (__attribute__((address_space(3))) void*)(l), 16, 0, 0);
}

#define BARX()  __builtin_amdgcn_s_barrier()
#define LGKM0() asm volatile("s_waitcnt lgkmcnt(0)" ::: "memory")
#define VMW0()  asm volatile("s_waitcnt vmcnt(0)" ::: "memory")

// A: stage one 128-row half-tile via global_load_lds (pre-swizzled source)
#define STGA(BUF, HALF, KT) do {                                                \
    gl2lds16(aSrc + (long)((HALF) * 128) * lda + (long)(KT) * 64,               \
             &As[BUF][(HALF) * 128 + w8][0]);                                   \
    gl2lds16(aSrc + (long)((HALF) * 128 + 64) * lda + (long)(KT) * 64,          \
             &As[BUF][(HALF) * 128 + 64 + w8][0]);                              \
} while (0)

// B: reg-staged fp32 -> bf16. Issue 64B contiguous per thread (4 x float4).
#define BISSUE(DST, BQ, KT) do {                                                \
    const float* p_ = (BQ) + (long)(KT) * 64;                                   \
    DST[0] = *reinterpret_cast<const float4*>(p_);                              \
    DST[1] = *reinterpret_cast<const float4*>(p_ + 4);                          \
    DST[2] = *reinterpret_cast<const float4*>(p_ + 8);                          \
    DST[3] = *reinterpret_cast<const float4*>(p_ + 12);                         \
} while (0)

// convert 16 floats -> 16 bf16, write two swizzled ds_write_b128
#define BWRITE(SRC, BUF, HALF) do {                                             \
    bf16x8 lo_ = { (bf16_t)SRC[0].x, (bf16_t)SRC[0].y, (bf16_t)SRC[0].z, (bf16_t)SRC[0].w, \
                   (bf16_t)SRC[1].x, (bf16_t)SRC[1].y, (bf16_t)SRC[1].z, (bf16_t)SRC[1].w }; \
    bf16x8 hi_ = { (bf16_t)SRC[2].x, (bf16_t)SRC[2].y, (bf16_t)SRC[2].z, (bf16_t)SRC[2].w, \
                   (bf16_t)SRC[3].x, (bf16_t)SRC[3].y, (bf16_t)SRC[3].z, (bf16_t)SRC[3].w }; \
    *reinterpret_cast<bf16x8*>(&Bs[BUF][(HALF) * 128 + trow][bc0sw]) = lo_;     \
    *reinterpret_cast<bf16x8*>(&Bs[BUF][(HALF) * 128 + trow][bc1sw]) = hi_;     \
} while (0)

#define LOADA(DST, BASE) do { _Pragma("unroll")                                 \
    for (int mi_ = 0; mi_ < 4; ++mi_) {                                         \
        DST[mi_][0] = *reinterpret_cast<const bf16x8*>((BASE) + aoff0 + mi_ * 1024); \
        DST[mi_][1] = *reinterpret_cast<const bf16x8*>((BASE) + aoff1 + mi_ * 1024); \
    } } while (0)

#define LOADB(DST, BASE) do { _Pragma("unroll")                                 \
    for (int ni_ = 0; ni_ < 2; ++ni_) {                                         \
        DST[ni_][0] = *reinterpret_cast<const bf16x8*>((BASE) + boff0 + ni_ * 1024); \
        DST[ni_][1] = *reinterpret_cast<const bf16x8*>((BASE) + boff1 + ni_ * 1024); \
    } } while (0)

#define MFMAQ(AF, BF, MIB, NIB) do {                                            \
    __builtin_amdgcn_s_setprio(1);                                              \
    _Pragma("unroll") for (int kk_ = 0; kk_ < 2; ++kk_)                         \
    _Pragma("unroll") for (int mi_ = 0; mi_ < 4; ++mi_)                         \
    _Pragma("unroll") for (int ni_ = 0; ni_ < 2; ++ni_)                         \
        acc[(MIB) + mi_][(NIB) + ni_] = __builtin_amdgcn_mfma_f32_16x16x32_bf16( \
            AF[mi_][kk_], BF[ni_][kk_], acc[(MIB) + mi_][(NIB) + ni_], 0, 0, 0); \
    __builtin_amdgcn_s_setprio(0);                                              \
} while (0)

// ---------- 256x256 8-phase BT GEMM; A via global_load_lds (bf16), B via
// reg-staged fp32->bf16 fused conversion. BRANCHLESS staging (clamped k-tile
// indices) so the compiler's vmcnt FIFO analysis stays exact; symmetric
// 3-phase-flight map:
//   bq(Bh0,tc2): issue P8(prev) -> write P3   (wait=vmcnt(4), drains A_b1)
//   bq2(Bh1,tc2): issue P1     -> write P4   (wait=vmcnt(8))
//   bq(Bh0,tc3): issue P4      -> write P7   (wait=vmcnt(4), drains A_b0)
//   bq2(Bh1,tc3): issue P5     -> write P8   (wait=vmcnt(8))
//   STGA A(tc2)@P4 lands by P7-drain (read next P1); A(tc3)@P8 by P3-drain.
// Last-iter staging re-reads tile nkt-1 into regions already past their last
// reader (WAR ledger: B halves free after P2/P6, A halves after P3/P7).
// EPI=0: gate/up-interleaved B (W1/W3), epilogue h = sigmoid(g)*u -> bf16.
// EPI=1: B = W2 direct, epilogue atomicAdd-scatter into out fp32.
template <int EPI>
__launch_bounds__(512, 2)
__global__ void k_gemm(const bf16_t* __restrict__ A, const float* __restrict__ Bf1,
                       const float* __restrict__ Bf3,
                       bf16_t* __restrict__ Hout, float* __restrict__ Fout,
                       const float* __restrict__ tw, const int* __restrict__ ids,
                       int Mtiles, int Ntiles, int nkt, int lda, long aStride) {
    __shared__ bf16_t As[2][256][64];
    __shared__ bf16_t Bs[2][256][64];

    // XCD-bijective swizzle (grid % 8 == 0), nt-major within expert
    const int nwg = gridDim.x;
    const int logical = (blockIdx.x & 7) * (nwg >> 3) + (blockIdx.x >> 3);
    const int tpe = Mtiles * Ntiles;
    const int e  = logical / tpe;
    const int r  = logical - e * tpe;
    const int nt = r / Mtiles;          // B-panel sharers are consecutive
    const int mt = r - nt * Mtiles;

    const int tid  = threadIdx.x;
    const int w    = tid >> 6;
    const int w8   = w * 8;
    const int lane = tid & 63;
    const int wr = w >> 2, wc = w & 3;        // 2(M) x 4(N) waves, 128x64/wave
    const int fr = lane & 15;
    const int fc = lane >> 4;

    // A staging source: pre-swizzled global chunk (involution c' = c ^ (row&7))
    const int srow = tid >> 3;
    const int schk = (tid & 7) ^ (srow & 7);
    const bf16_t* aSrc = A + (long)e * aStride + ((long)mt * 256 + srow) * lda + schk * 8;

    // B staging: thread owns row trow of each half-tile, chunks tc0, tc0+1
    const int trow = tid >> 2;                  // 0..127
    const int tc0  = (tid & 3) * 2;
    const int bsw  = trow & 7;
    const int bc0sw = (tc0 ^ bsw) * 8;
    const int bc1sw = ((tc0 + 1) ^ bsw) * 8;
    const float* bQ0;
    const float* bQ1;
    if constexpr (EPI == 0) {
        // inverse of the gate/up interleave: n' -> (sel, n)
        int n0 = nt * 256 + trow;
        int n1 = n0 + 128;
        int s0 = (n0 >> 4) & 1, s1 = (n1 >> 4) & 1;
        int r0 = ((n0 >> 5) << 4) | (n0 & 15);
        int r1 = ((n1 >> 5) << 4) | (n1 & 15);
        bQ0 = (s0 ? Bf3 : Bf1) + ((long)e * DN + r0) * DK + tc0 * 8;
        bQ1 = (s1 ? Bf3 : Bf1) + ((long)e * DN + r1) * DK + tc0 * 8;
    } else {
        bQ0 = Bf1 + (long)e * DK * DN + ((long)nt * 256 + trow) * DN + tc0 * 8;
        bQ1 = bQ0 + 128L * DN;
    }

    // ds_read element offsets (swizzled)
    const int sx = lane & 7;
    const int aoff0 = (wr * 128 + fr) * 64 + ((0 + fc) ^ sx) * 8;
    const int aoff1 = (wr * 128 + fr) * 64 + ((4 + fc) ^ sx) * 8;
    const int boff0 = (wc * 64 + fr) * 64 + ((0 + fc) ^ sx) * 8;
    const int boff1 = (wc * 64 + fr) * 64 + ((4 + fc) ^ sx) * 8;

    const bf16_t* As0 = &As[0][0][0];
    const bf16_t* As1 = &As[1][0][0];
    const bf16_t* Bs0 = &Bs[0][0][0];
    const bf16_t* Bs1 = &Bs[1][0][0];

    bf16x8 af[4][2], ah[4][2], bl[2][2], bh[2][2];
    float4 bq[4], bq2[4];

    const int last = nkt - 1;

    // ---- prologue: establish steady-state in-flight set {A_b1 x4, bq x4} ----
    {
        float4 p0[4], p1[4], p2[4], p3[4];
        STGA(0, 0, 0); STGA(0, 1, 0);               // A_b0 x4
        BISSUE(p0, bQ0, 0); BISSUE(p1, bQ1, 0);
        BISSUE(p2, bQ0, 1); BISSUE(p3, bQ1, 1);
        BWRITE(p0, 0, 0); BWRITE(p1, 0, 1);         // wait p3 drains A_b0 + p*
        BWRITE(p2, 1, 0); BWRITE(p3, 1, 1);
        STGA(1, 0, 1); STGA(1, 1, 1);               // A_b1 x4 (stays in flight)
        BISSUE(bq, bQ0, 2 < last ? 2 : last);       // bq x4 (stays in flight)
        LGKM0();
    }
    BARX();

    f32x4 acc[8][4];
#pragma unroll
    for (int a = 0; a < 8; ++a)
#pragma unroll
        for (int b = 0; b < 4; ++b) acc[a][b] = (f32x4){0.f, 0.f, 0.f, 0.f};

    const int nIter = nkt >> 1;
    for (int it = 0; it < nIter; ++it) {
        const int t = it * 2;
        const int tc2 = t + 2 < last ? t + 2 : last;
        const int tc3 = t + 3 < last ? t + 3 : last;
        const int tc4 = t + 4 < last ? t + 4 : last;
        // P1: read af,bl (b0) | issue bq2 = Bh1(tc2)
        LOADA(af, As0); LOADB(bl, Bs0);
        BISSUE(bq2, bQ1, tc2);
        BARX(); LGKM0();
        MFMAQ(af, bl, 0, 0);
        BARX();
        // P2: read bh (b0)
        LOADB(bh, Bs0 + 2048);
        BARX(); LGKM0();
        MFMAQ(af, bh, 0, 2);
        BARX();
        // P3: read ah (b0) | write bq -> b0.Bh0 (vmcnt(4): drains A_b1, leaves bq2)
        LOADA(ah, As0 + 4096);
        BWRITE(bq, 0, 0);
        BARX(); LGKM0();
        MFMAQ(ah, bh, 4, 2);
        BARX();
        // P4: stage A(tc2)->b0 | issue bq = Bh0(tc3) | write bq2 -> b0.Bh1 (vmcnt(8))
        STGA(0, 0, tc2); STGA(0, 1, tc2);
        BISSUE(bq, bQ0, tc3);
        BWRITE(bq2, 0, 1);
        BARX();
        MFMAQ(ah, bl, 4, 0);
        BARX();
        // P5: read af,bl (b1) | issue bq2 = Bh1(tc3)
        LOADA(af, As1); LOADB(bl, Bs1);
        BISSUE(bq2, bQ1, tc3);
        BARX(); LGKM0();
        MFMAQ(af, bl, 0, 0);
        BARX();
        // P6: read bh (b1)
        LOADB(bh, Bs1 + 2048);
        BARX(); LGKM0();
        MFMAQ(af, bh, 0, 2);
        BARX();
        // P7: read ah (b1) | write bq -> b1.Bh0 (vmcnt(4): drains A_b0, leaves bq2)
        LOADA(ah, As1 + 4096);
        BWRITE(bq, 1, 0);
        BARX(); LGKM0();
        MFMAQ(ah, bh, 4, 2);
        BARX();
        // P8: stage A(tc3)->b1 | issue bq = Bh0(next tc2) | write bq2 -> b1.Bh1 (vmcnt(8))
        STGA(1, 0, tc3); STGA(1, 1, tc3);
        BISSUE(bq, bQ0, tc4);
        BWRITE(bq2, 1, 1);
        BARX();
        MFMAQ(ah, bl, 4, 0);
        BARX();
    }
    VMW0();

    if constexpr (EPI == 0) {
        // interleaved cols: ni even = gate, ni odd = up (same real n)
        const long prow0 = (long)e * PPE + (long)mt * 256 + wr * 128 + fc * 4;
        const int col0 = nt * 128 + wc * 32 + fr;
#pragma unroll
        for (int mi = 0; mi < 8; ++mi)
#pragma unroll
            for (int i = 0; i < 4; ++i) {
                long row = prow0 + mi * 16 + i;
#pragma unroll
                for (int p = 0; p < 2; ++p) {
                    float g = acc[mi][2 * p][i];
                    float u = acc[mi][2 * p + 1][i];
                    float s = 1.f / (1.f + __expf(-g));
                    Hout[row * DN + col0 + p * 16] = (bf16_t)(s * u);
                }
            }
    } else {
        const int p0 = e * PPE + mt * 256 + wr * 128 + fc * 4;
        const int col0 = nt * 256 + wc * 64 + fr;
#pragma unroll
        for (int mi = 0; mi < 8; ++mi)
#pragma unroll
            for (int i = 0; i < 4; ++i) {
                int gp = p0 + mi * 16 + i;
                float wgt = tw[gp];
                float* ob = Fout + (long)ids[gp] * DK + col0;
#pragma unroll
                for (int ni = 0; ni < 4; ++ni)
                    atomicAdd(ob + ni * 16, acc[mi][ni][i] * wgt);
            }
    }
}

extern "C" void kernel_launch(void* const* d_in, const int* in_sizes, int n_in,
                              void* d_out, int out_size, void* d_ws, size_t ws_size,
                              hipStream_t stream) {
    const float* x   = (const float*)d_in[0];
    const float* W1  = (const float*)d_in[1];
    const float* W3  = (const float*)d_in[2];
    const float* W2  = (const float*)d_in[3];
    const float* tw  = (const float*)d_in[4];
    const int*   sid = (const int*)d_in[5];
    float* out = (float*)d_out;

    // workspace: xg 32MB, h 44MB
    char* ws = (char*)d_ws;
    bf16_t* xg = (bf16_t*)ws;
    bf16_t* h  = (bf16_t*)(ws + 33554432L);

    hipMemsetAsync(d_out, 0, (size_t)out_size * sizeof(float), stream);
    k_gather<<<NP * (DK / 4) / 256, 256, 0, stream>>>(x, sid, xg);

    // GEMM1+act: h = sigmoid(xg.W1^T) * (xg.W3^T); W1/W3 read fp32 directly
    k_gemm<0><<<NEXP * 4 * 22, 512, 0, stream>>>(
        xg, W1, W3, h, nullptr, nullptr, nullptr,
        4, 22, 32, DK, (long)PPE * DK);

    // GEMM2: out[tok,k] += tw[p] * h[p,:] . W2[e,k,:]^T; W2 read fp32 directly
    k_gemm<1><<<NEXP * 4 * 8, 512, 0, stream>>>(
        h, W2, nullptr, nullptr, out, tw, sid,
        4, 8, 44, DN, (long)PPE * DN);
}

// Round 8
// 519.013 us; speedup vs baseline: 1.0786x; 1.0786x over previous
//
#include <hip/hip_runtime.h>
#include <hip/hip_bf16.h>
#include <cstdint>

typedef __bf16 bf16_t;
typedef __attribute__((ext_vector_type(8))) __bf16 bf16x8;
typedef __attribute__((ext_vector_type(4))) __bf16 bf16x4;
typedef __attribute__((ext_vector_type(4))) float f32x4;

#define NEXP 8
#define DK   2048
#define DN   2816
#define DN2  5632
#define NP   8192
#define PPE  1024

// ---------- W1+W3 -> interleaved [E][5632][K]: 16-row groups alternate gate/up ----------
__global__ void k_cvt_w13(const float* __restrict__ W1, const float* __restrict__ W3,
                          bf16_t* __restrict__ dst) {
    const int total4 = NEXP * DN * (DK / 4);
    int stride = gridDim.x * blockDim.x;
    for (int i = blockIdx.x * blockDim.x + threadIdx.x; i < 2 * total4; i += stride) {
        int sel = i >= total4;
        int j   = sel ? i - total4 : i;
        int g   = j >> 9;           // source row (K/4 = 512 vec4 per row)
        int c4  = j & 511;
        int e   = g / DN;
        int n   = g - e * DN;
        long drow = (long)e * DN2 + ((n >> 4) << 5) + (n & 15) + (sel ? 16 : 0);
        float4 v = reinterpret_cast<const float4*>(sel ? W3 : W1)[j];
        bf16x4 o = { (bf16_t)v.x, (bf16_t)v.y, (bf16_t)v.z, (bf16_t)v.w };
        *reinterpret_cast<bf16x4*>(dst + drow * DK + c4 * 4) = o;
    }
}

// ---------- flat fp32 -> bf16 ----------
__global__ void k_cvt(const float* __restrict__ src, bf16_t* __restrict__ dst, int total4) {
    int stride = gridDim.x * blockDim.x;
    for (int i = blockIdx.x * blockDim.x + threadIdx.x; i < total4; i += stride) {
        float4 v = reinterpret_cast<const float4*>(src)[i];
        bf16x4 o = { (bf16_t)v.x, (bf16_t)v.y, (bf16_t)v.z, (bf16_t)v.w };
        reinterpret_cast<bf16x4*>(dst)[i] = o;
    }
}

// ---------- gather x rows by sorted_token_ids, convert to bf16 ----------
__global__ void k_gather(const float* __restrict__ x, const int* __restrict__ ids,
                         bf16_t* __restrict__ xg) {
    int i = blockIdx.x * blockDim.x + threadIdx.x;
    if (i >= NP * (DK / 4)) return;
    int p  = i >> 9;
    int c4 = i & 511;
    int tok = ids[p];
    float4 v = reinterpret_cast<const float4*>(x + (size_t)tok * DK)[c4];
    bf16x4 o = { (bf16_t)v.x, (bf16_t)v.y, (bf16_t)v.z, (bf16_t)v.w };
    *reinterpret_cast<bf16x4*>(xg + (size_t)p * DK + c4 * 4) = o;
}

// ---------- async global->LDS, 16B per lane (wave-uniform LDS base) ----------
__device__ __forceinline__ void gl2lds16(const bf16_t* g, bf16_t* l) {
    __builtin_amdgcn_global_load_lds(
        (__attribute__((address_space(1))) void*)(const_cast<bf16_t*>(g)),
        (__attribute__((address_space(3))) void*)(l), 16, 0, 0);
}

#define BARX() __builtin_amdgcn_s_barrier()
#define LGKM0() asm volatile("s_waitcnt lgkmcnt(0)" ::: "memory")
#define VMW4() asm volatile("s_waitcnt vmcnt(4)" ::: "memory")
#define VMW0() asm volatile("s_waitcnt vmcnt(0)" ::: "memory")

// stage one 128-row half-tile (2 x global_load_lds per thread, 16B each)
#define STG(ARR, SRC, LD, BUF, HALF, KT) do {                                   \
    gl2lds16((SRC) + (long)((HALF) * 128) * (LD) + (long)(KT) * 64,             \
             &ARR[BUF][(HALF) * 128 + w8][0]);                                  \
    gl2lds16((SRC) + (long)((HALF) * 128 + 64) * (LD) + (long)(KT) * 64,        \
             &ARR[BUF][(HALF) * 128 + 64 + w8][0]);                             \
} while (0)

#define LOADA(DST, BASE) do { _Pragma("unroll")                                 \
    for (int mi_ = 0; mi_ < 4; ++mi_) {                                         \
        DST[mi_][0] = *reinterpret_cast<const bf16x8*>((BASE) + aoff0 + mi_ * 1024); \
        DST[mi_][1] = *reinterpret_cast<const bf16x8*>((BASE) + aoff1 + mi_ * 1024); \
    } } while (0)

#define LOADB(DST, BASE) do { _Pragma("unroll")                                 \
    for (int ni_ = 0; ni_ < 2; ++ni_) {                                         \
        DST[ni_][0] = *reinterpret_cast<const bf16x8*>((BASE) + boff0 + ni_ * 1024); \
        DST[ni_][1] = *reinterpret_cast<const bf16x8*>((BASE) + boff1 + ni_ * 1024); \
    } } while (0)

#define MFMAQ(AF, BF, MIB, NIB) do {                                            \
    __builtin_amdgcn_s_setprio(1);                                              \
    _Pragma("unroll") for (int kk_ = 0; kk_ < 2; ++kk_)                         \
    _Pragma("unroll") for (int mi_ = 0; mi_ < 4; ++mi_)                         \
    _Pragma("unroll") for (int ni_ = 0; ni_ < 2; ++ni_)                         \
        acc[(MIB) + mi_][(NIB) + ni_] = __builtin_amdgcn_mfma_f32_16x16x32_bf16( \
            AF[mi_][kk_], BF[ni_][kk_], acc[(MIB) + mi_][(NIB) + ni_], 0, 0, 0); \
    __builtin_amdgcn_s_setprio(0);                                              \
} while (0)

// ---------- 256x256 8-phase BT GEMM, XOR-swizzled LDS (R2-proven schedule) ----
// Staging: P1:A0(t+1) P2:A1(t+1) P3:B0(t+2) P4:B1(t+2)+VMW4 (drains A(t+1),
// keeps B(t+2)x4 in flight) P5:A0(t+2) P6:A1(t+2) P7:B0(t+3) P8:B1(t+3)+VMW4.
// nt-major block order: Mtiles blocks sharing a B-panel are consecutive
// logical ids -> co-resident on one XCD -> B served from L2 (R4: FETCH -53%).
// EPI=0: fused sigmoid(gate)*up epilogue (interleaved B), writes h bf16 [NP][DN].
// EPI=1: scale by tw[pair], atomicAdd scatter into out fp32 [NTOK][DK].
template <int EPI>
__launch_bounds__(512, 2)
__global__ void k_gemm(const bf16_t* __restrict__ A, const bf16_t* __restrict__ B,
                       bf16_t* __restrict__ Hout, float* __restrict__ Fout,
                       const float* __restrict__ tw, const int* __restrict__ ids,
                       int Mtiles, int Ntiles, int nkt, int lda, int ldb,
                       long aStride, long bStride) {
    __shared__ bf16_t As[2][256][64];
    __shared__ bf16_t Bs[2][256][64];

    // XCD-bijective swizzle (grid % 8 == 0): each XCD gets one contiguous chunk
    const int nwg = gridDim.x;
    const int logical = (blockIdx.x & 7) * (nwg >> 3) + (blockIdx.x >> 3);
    const int tpe = Mtiles * Ntiles;
    const int e  = logical / tpe;
    const int r  = logical - e * tpe;
    const int nt = r / Mtiles;          // nt-major: B-panel sharers consecutive
    const int mt = r - nt * Mtiles;

    const int tid  = threadIdx.x;
    const int w    = tid >> 6;
    const int w8   = w * 8;
    const int lane = tid & 63;
    const int wr = w >> 2, wc = w & 3;        // 2(M) x 4(N) wave grid, 128x64/wave
    const int fr = lane & 15;
    const int fc = lane >> 4;

    // staging source: pre-swizzled global chunk (involution: c' = c ^ (row&7))
    const int srow = tid >> 3;                 // 0..63
    const int schk = (tid & 7) ^ (srow & 7);
    const bf16_t* aSrc = A + (long)e * aStride + ((long)mt * 256 + srow) * lda + schk * 8;
    const bf16_t* bSrc = B + (long)e * bStride + ((long)nt * 256 + srow) * ldb + schk * 8;

    // ds_read element offsets (swizzled): row*64 + (chunk ^ (row&7))*8
    const int sx = lane & 7;
    const int aoff0 = (wr * 128 + fr) * 64 + ((0 + fc) ^ sx) * 8;  // kk=0
    const int aoff1 = (wr * 128 + fr) * 64 + ((4 + fc) ^ sx) * 8;  // kk=1
    const int boff0 = (wc * 64 + fr) * 64 + ((0 + fc) ^ sx) * 8;
    const int boff1 = (wc * 64 + fr) * 64 + ((4 + fc) ^ sx) * 8;

    const bf16_t* As0 = &As[0][0][0];
    const bf16_t* As1 = &As[1][0][0];
    const bf16_t* Bs0 = &Bs[0][0][0];
    const bf16_t* Bs1 = &Bs[1][0][0];

    f32x4 acc[8][4];
#pragma unroll
    for (int a = 0; a < 8; ++a)
#pragma unroll
        for (int b = 0; b < 4; ++b) acc[a][b] = (f32x4){0.f, 0.f, 0.f, 0.f};

    bf16x8 af[4][2], ah[4][2], bl[2][2], bh[2][2];

    // prologue: tile0 full -> buf0, tile1 B halves -> buf1
    STG(As, aSrc, lda, 0, 0, 0); STG(As, aSrc, lda, 0, 1, 0);
    STG(Bs, bSrc, ldb, 0, 0, 0); STG(Bs, bSrc, ldb, 0, 1, 0);
    STG(Bs, bSrc, ldb, 1, 0, 1); STG(Bs, bSrc, ldb, 1, 1, 1);
    VMW4();           // tile0's 8 loads landed (tile1 B stays in flight)
    BARX();

    const int nIter = nkt >> 1;
    for (int it = 0; it < nIter; ++it) {
        const int t = it * 2;
        const bool last = (it == nIter - 1);
        // P1: buf0 a-lo,b-lo | stage buf1.A0(t+1)
        LOADA(af, As0); LOADB(bl, Bs0);
        STG(As, aSrc, lda, 1, 0, t + 1);
        BARX(); LGKM0();
        MFMAQ(af, bl, 0, 0);
        BARX();
        // P2: b-hi | stage buf1.A1(t+1)
        LOADB(bh, Bs0 + 2048);
        STG(As, aSrc, lda, 1, 1, t + 1);
        BARX(); LGKM0();
        MFMAQ(af, bh, 0, 2);
        BARX();
        // P3: a-hi | stage buf0.B0(t+2)
        LOADA(ah, As0 + 4096);
        if (!last) STG(Bs, bSrc, ldb, 0, 0, t + 2);
        BARX(); LGKM0();
        MFMAQ(ah, bh, 4, 2);
        BARX();
        // P4: stage buf0.B1(t+2) | VMW4: A(t+1) landed, B(t+2)x4 stay in flight
        if (!last) { STG(Bs, bSrc, ldb, 0, 1, t + 2); VMW4(); } else { VMW0(); }
        BARX();
        MFMAQ(ah, bl, 4, 0);
        BARX();
        // P5: buf1 a-lo,b-lo | stage buf0.A0(t+2)
        LOADA(af, As1); LOADB(bl, Bs1);
        if (!last) STG(As, aSrc, lda, 0, 0, t + 2);
        BARX(); LGKM0();
        MFMAQ(af, bl, 0, 0);
        BARX();
        // P6: b-hi | stage buf0.A1(t+2)
        LOADB(bh, Bs1 + 2048);
        if (!last) STG(As, aSrc, lda, 0, 1, t + 2);
        BARX(); LGKM0();
        MFMAQ(af, bh, 0, 2);
        BARX();
        // P7: a-hi | stage buf1.B0(t+3)
        LOADA(ah, As1 + 4096);
        if (!last) STG(Bs, bSrc, ldb, 1, 0, t + 3);
        BARX(); LGKM0();
        MFMAQ(ah, bh, 4, 2);
        BARX();
        // P8: stage buf1.B1(t+3) | VMW4: B(t+2)+A(t+2) landed for next iter
        if (!last) { STG(Bs, bSrc, ldb, 1, 1, t + 3); VMW4(); } else { VMW0(); }
        BARX();
        MFMAQ(ah, bl, 4, 0);
        BARX();
    }

    if constexpr (EPI == 0) {
        // interleaved cols: ni even = gate, ni odd = up (same real n)
        const long prow0 = (long)e * PPE + (long)mt * 256 + wr * 128 + fc * 4;
        const int col0 = nt * 128 + wc * 32 + fr;
#pragma unroll
        for (int mi = 0; mi < 8; ++mi)
#pragma unroll
            for (int i = 0; i < 4; ++i) {
                long row = prow0 + mi * 16 + i;
#pragma unroll
                for (int p = 0; p < 2; ++p) {
                    float g = acc[mi][2 * p][i];
                    float u = acc[mi][2 * p + 1][i];
                    float s = 1.f / (1.f + __expf(-g));
                    Hout[row * DN + col0 + p * 16] = (bf16_t)(s * u);
                }
            }
    } else {
        const int p0 = e * PPE + mt * 256 + wr * 128 + fc * 4;
        const int col0 = nt * 256 + wc * 64 + fr;
#pragma unroll
        for (int mi = 0; mi < 8; ++mi)
#pragma unroll
            for (int i = 0; i < 4; ++i) {
                int gp = p0 + mi * 16 + i;
                float wgt = tw[gp];
                float* ob = Fout + (long)ids[gp] * DK + col0;
#pragma unroll
                for (int ni = 0; ni < 4; ++ni)
                    atomicAdd(ob + ni * 16, acc[mi][ni][i] * wgt);
            }
    }
}

extern "C" void kernel_launch(void* const* d_in, const int* in_sizes, int n_in,
                              void* d_out, int out_size, void* d_ws, size_t ws_size,
                              hipStream_t stream) {
    const float* x   = (const float*)d_in[0];
    const float* W1  = (const float*)d_in[1];
    const float* W3  = (const float*)d_in[2];
    const float* W2  = (const float*)d_in[3];
    const float* tw  = (const float*)d_in[4];
    const int*   sid = (const int*)d_in[5];
    float* out = (float*)d_out;

    // workspace layout (~340 MB)
    char* ws = (char*)d_ws;
    bf16_t* w13i = (bf16_t*)ws;                      // [E][5632][2048] interleaved, 176MB
    bf16_t* w2b  = (bf16_t*)(ws + 184549376L);       // [E][2048][2816],             88MB
    bf16_t* xg   = (bf16_t*)(ws + 276824064L);       // [8192][2048],                32MB
    bf16_t* h    = (bf16_t*)(ws + 310378496L);       // [8192][2816],                44MB

    hipMemsetAsync(d_out, 0, (size_t)out_size * sizeof(float), stream);

    k_cvt_w13<<<2048, 256, 0, stream>>>(W1, W3, w13i);
    k_cvt<<<2048, 256, 0, stream>>>(W2, w2b, NEXP * DK * (DN / 4));
    k_gather<<<NP * (DK / 4) / 256, 256, 0, stream>>>(x, sid, xg);

    // GEMM1+act: h[p,n] = sigmoid(xg.W1^T) * (xg.W3^T), interleaved weights
    k_gemm<0><<<NEXP * 4 * 22, 512, 0, stream>>>(
        xg, w13i, h, nullptr, nullptr, nullptr,
        4, 22, 32, DK, DK, (long)PPE * DK, (long)DN2 * DK);

    // GEMM2: out[tok,k] += tw[p] * h[p,:] . w2b[e,k,:]^T
    k_gemm<1><<<NEXP * 4 * 8, 512, 0, stream>>>(
        h, w2b, nullptr, out, tw, sid,
        4, 8, 44, DN, DN, (long)PPE * DN, (long)DK * DN);
}